// Round 2
// baseline (115.023 us; speedup 1.0000x reference)
//
#include <hip/hip_runtime.h>

// Problem constants (from reference): T=128, B=1, H=W=32 (HW=1024), F=512.
// e[t] = (1/1024) * sum_{s<1024, f<512} x[t, s, f] * Wx[f]   (+ att_h, which is
// constant across t and cancels exactly inside softmax -> skipped).
// out = softmax_t(e), shape [128,1,1,1] float32.
//
// Single fused kernel: 2048 blocks compute per-block partial dots; the last
// block to finish (device-scope atomic counter) performs the 128-wide softmax.

#define T_STEPS 128
#define HW      1024
#define F4      128                       // F/4 float4 per (t, spatial) row
#define BPT     16                        // blocks per timestep
#define THREADS 256
#define NBLOCKS (T_STEPS * BPT)           // 2048
#define F4_PER_BLOCK (HW * F4 / BPT)      // 8192 float4 per block
#define ITERS   (F4_PER_BLOCK / THREADS)  // 32 float4 per thread

__global__ __launch_bounds__(THREADS) void ta_fused_kernel(
    const float4* __restrict__ x, const float* __restrict__ Wx,
    float* __restrict__ partial, unsigned int* __restrict__ counter,
    float* __restrict__ out)
{
    const int tid = threadIdx.x;
    const int t   = blockIdx.x / BPT;
    const int b   = blockIdx.x % BPT;

    // Thread's float4 index within t advances by 256 each iter; 256 % 128 == 0,
    // so the Wx fragment (f4 = idx & 127) is loop-invariant per thread.
    const float4 w = reinterpret_cast<const float4*>(Wx)[tid & (F4 - 1)];

    const float4* xt = x + (size_t)t * (HW * F4) + b * F4_PER_BLOCK + tid;

    float acc = 0.0f;
#pragma unroll
    for (int i = 0; i < ITERS; ++i) {
        float4 v = xt[(size_t)i * THREADS];
        acc = fmaf(v.x, w.x, acc);
        acc = fmaf(v.y, w.y, acc);
        acc = fmaf(v.z, w.z, acc);
        acc = fmaf(v.w, w.w, acc);
    }

    // wave (64-lane) butterfly reduce
    for (int o = 32; o > 0; o >>= 1) acc += __shfl_xor(acc, o);

    __shared__ float s[THREADS / 64];
    __shared__ unsigned int s_old;
    if ((tid & 63) == 0) s[tid >> 6] = acc;
    __syncthreads();

    if (tid == 0) {
        partial[blockIdx.x] = s[0] + s[1] + s[2] + s[3];
        __threadfence();                         // partial visible device-wide
        s_old = atomicAdd(counter, 1u);          // device-scope by default
    }
    __syncthreads();
    if (s_old != NBLOCKS - 1) return;

    // ---- last block: softmax over 128 timesteps (threads 0..127) ----
    __threadfence();                             // acquire side
    __shared__ float smax[2], ssum[2];

    if (tid < T_STEPS) {
        float e = 0.0f;
#pragma unroll
        for (int i = 0; i < BPT; ++i)
            e += __hip_atomic_load(&partial[tid * BPT + i],
                                   __ATOMIC_ACQUIRE, __HIP_MEMORY_SCOPE_AGENT);
        e *= (1.0f / (float)HW);

        float m = e;
        for (int o = 32; o > 0; o >>= 1) m = fmaxf(m, __shfl_xor(m, o));
        const int wave = tid >> 6;
        if ((tid & 63) == 0) smax[wave] = m;
        __syncthreads();
        const float gm = fmaxf(smax[0], smax[1]);

        const float ex = expf(e - gm);
        float sm = ex;
        for (int o = 32; o > 0; o >>= 1) sm += __shfl_xor(sm, o);
        if ((tid & 63) == 0) ssum[wave] = sm;
        __syncthreads();

        out[tid] = ex / (ssum[0] + ssum[1]);
    }
}

extern "C" void kernel_launch(void* const* d_in, const int* in_sizes, int n_in,
                              void* d_out, int out_size, void* d_ws, size_t ws_size,
                              hipStream_t stream) {
    const float* x  = (const float*)d_in[0];   // [128,1,32,32,512] f32
    // d_in[1] = h, d_in[3] = Wh: their contribution is constant over t and
    // cancels exactly in softmax -> not read.
    const float* Wx = (const float*)d_in[2];   // [1,512] f32

    float*        partial = (float*)d_ws;                       // 2048 floats
    unsigned int* counter = (unsigned int*)((char*)d_ws + NBLOCKS * sizeof(float));
    float*        out     = (float*)d_out;                      // 128 floats

    // Counter must start at 0 every call (d_ws is poisoned once, not re-poisoned).
    hipMemsetAsync(counter, 0, sizeof(unsigned int), stream);

    ta_fused_kernel<<<NBLOCKS, THREADS, 0, stream>>>(
        (const float4*)x, Wx, partial, counter, out);
}

// Round 4
// 45.146 us; speedup vs baseline: 2.5478x; 2.5478x over previous
//
#include <hip/hip_runtime.h>

// Problem constants (from reference): T=128, B=1, H=W=32 (HW=1024), F=512.
// e[t] = (1/1024) * sum_{s<1024, f<512} x[t, s, f] * Wx[f]   (+ att_h, which is
// constant across t and cancels exactly inside softmax -> skipped).
// out = softmax_t(e), shape [128,1,1,1] float32.
//
// Two-kernel structure (R2 post-mortem: last-block fusion is fence-bound on
// CDNA4 -- per-block device-scope release = L2 writeback, 2048x = +70us).
// Kernel 1 streams x at HBM rate with non-temporal float4 loads
// (Clang ext_vector_type: __builtin_nontemporal_load rejects HIP_vector_type).

#define T_STEPS 128
#define HW      1024
#define F4      128                       // F/4 float4 per (t, spatial) row
#define BPT     16                        // blocks per timestep
#define THREADS 256
#define F4_PER_BLOCK (HW * F4 / BPT)      // 8192 float4 per block
#define ITERS   (F4_PER_BLOCK / THREADS)  // 32 float4 per thread

typedef float f32x4 __attribute__((ext_vector_type(4)));

__global__ __launch_bounds__(THREADS) void ta_dot_kernel(
    const f32x4* __restrict__ x, const float* __restrict__ Wx,
    float* __restrict__ partial)
{
    const int tid = threadIdx.x;
    const int t   = blockIdx.x / BPT;
    const int b   = blockIdx.x % BPT;

    // Thread's float4 index within t advances by 256 each iter; 256 % 128 == 0,
    // so the Wx fragment (f4 = idx & 127) is loop-invariant per thread.
    const f32x4 w = reinterpret_cast<const f32x4*>(Wx)[tid & (F4 - 1)];

    const f32x4* xt = x + (size_t)t * (HW * F4) + b * F4_PER_BLOCK + tid;

    float acc = 0.0f;
#pragma unroll
    for (int i = 0; i < ITERS; ++i) {
        f32x4 v = __builtin_nontemporal_load(&xt[(size_t)i * THREADS]);
        acc = fmaf(v.x, w.x, acc);
        acc = fmaf(v.y, w.y, acc);
        acc = fmaf(v.z, w.z, acc);
        acc = fmaf(v.w, w.w, acc);
    }

    // wave (64-lane) butterfly reduce
    for (int o = 32; o > 0; o >>= 1) acc += __shfl_xor(acc, o);

    __shared__ float s[THREADS / 64];
    if ((tid & 63) == 0) s[tid >> 6] = acc;
    __syncthreads();
    if (tid == 0) partial[blockIdx.x] = s[0] + s[1] + s[2] + s[3];
}

__global__ __launch_bounds__(T_STEPS) void ta_softmax_kernel(
    const float* __restrict__ partial, float* __restrict__ out)
{
    const int tid = threadIdx.x;  // 0..127, one thread per timestep

    float e = 0.0f;
#pragma unroll
    for (int i = 0; i < BPT; ++i) e += partial[tid * BPT + i];
    e *= (1.0f / (float)HW);

    // max over 128 values: 64-lane shuffle reduce, then combine 2 waves via LDS
    float m = e;
    for (int o = 32; o > 0; o >>= 1) m = fmaxf(m, __shfl_xor(m, o));

    __shared__ float smax[2], ssum[2];
    const int wave = tid >> 6;
    if ((tid & 63) == 0) smax[wave] = m;
    __syncthreads();
    const float gm = fmaxf(smax[0], smax[1]);

    const float ex = expf(e - gm);
    float s = ex;
    for (int o = 32; o > 0; o >>= 1) s += __shfl_xor(s, o);
    if ((tid & 63) == 0) ssum[wave] = s;
    __syncthreads();

    out[tid] = ex / (ssum[0] + ssum[1]);
}

extern "C" void kernel_launch(void* const* d_in, const int* in_sizes, int n_in,
                              void* d_out, int out_size, void* d_ws, size_t ws_size,
                              hipStream_t stream) {
    const float* x  = (const float*)d_in[0];   // [128,1,32,32,512] f32
    // d_in[1] = h, d_in[3] = Wh: their contribution is constant over t and
    // cancels exactly in softmax -> not read.
    const float* Wx = (const float*)d_in[2];   // [1,512] f32

    float* partial = (float*)d_ws;             // 128*16 floats, fully overwritten
    float* out     = (float*)d_out;            // 128 floats

    ta_dot_kernel<<<T_STEPS * BPT, THREADS, 0, stream>>>(
        (const f32x4*)x, Wx, partial);
    ta_softmax_kernel<<<1, T_STEPS, 0, stream>>>(partial, out);
}